// Round 14
// baseline (66.126 us; speedup 1.0000x reference)
//
#include <hip/hip_runtime.h>

#define Nn 1024
#define Ee 65536
#define Pq 1024
#define CAP 160

typedef unsigned long long ull;

// ---------------- zero-init (degI 4KB + Mbit 128KB + MTbit 128KB = 266240 B = 65x256x16B) ----------------
__global__ __launch_bounds__(256) void k_zero(uint4* __restrict__ z) {
    z[blockIdx.x * 256 + threadIdx.x] = make_uint4(0, 0, 0, 0);
}

// ---------------- fused front, role-split 512 blocks ----------------
// Blocks 0-255: xw1 = x @ Wg1. Blocks 256-511: edge pass (deg, padded adj, bitmaps).
__global__ __launch_bounds__(256) void k_front(const float* __restrict__ x,
                                               const float* __restrict__ Wg1,
                                               float* __restrict__ xw1,
                                               const int* __restrict__ ei,
                                               int* __restrict__ degI,
                                               int* __restrict__ adj,
                                               ull* __restrict__ Mbit,
                                               ull* __restrict__ MTbit) {
    __shared__ float sW[8192];
    int tid = threadIdx.x;
    int B = blockIdx.x;
    if (B < 256) {
        int gid = B * 256 + tid;
        for (int i = tid; i < 2048; i += 256)
            ((float4*)sW)[i] = ((const float4*)Wg1)[i];
        __syncthreads();
        int lane = gid & 63;
        int r = __builtin_amdgcn_readfirstlane(gid >> 6);
        const float* xr = x + r * 128;
        float acc = 0.f;
        #pragma unroll 8
        for (int j = 0; j < 128; ++j) acc = fmaf(xr[j], sW[j * 64 + lane], acc);
        xw1[gid] = acc;
    } else {
        int e = (B - 256) * 256 + tid;
        int r = ei[e], c = ei[Ee + e];
        int slot = atomicAdd(&degI[c], 1);
        if (slot < CAP) adj[c * CAP + slot] = r;
        atomicOr(&Mbit[r * 16 + (c >> 6)], 1ull << (c & 63));
        atomicOr(&MTbit[c * 16 + (r >> 6)], 1ull << (r & 63));
    }
}

// ---------------- gather core (gather1): LDS-resident adjacency, 4 waves split, 8-deep ILP ----------------
__device__ __forceinline__ float gather_quarter(const int* __restrict__ s_adj,
                                                const float* __restrict__ xwsrc,
                                                const float* s_dinv, int w,
                                                int n, int lane) {
    float acc = 0.f;
    int j = w, end = n;
    for (; j + 28 < end; j += 32) {
        int r0 = s_adj[j],      r1 = s_adj[j + 4],  r2 = s_adj[j + 8],  r3 = s_adj[j + 12];
        int r4 = s_adj[j + 16], r5 = s_adj[j + 20], r6 = s_adj[j + 24], r7 = s_adj[j + 28];
        float a0 = xwsrc[r0 * 64 + lane] * s_dinv[r0];
        float a1 = xwsrc[r1 * 64 + lane] * s_dinv[r1];
        float a2 = xwsrc[r2 * 64 + lane] * s_dinv[r2];
        float a3 = xwsrc[r3 * 64 + lane] * s_dinv[r3];
        float a4 = xwsrc[r4 * 64 + lane] * s_dinv[r4];
        float a5 = xwsrc[r5 * 64 + lane] * s_dinv[r5];
        float a6 = xwsrc[r6 * 64 + lane] * s_dinv[r6];
        float a7 = xwsrc[r7 * 64 + lane] * s_dinv[r7];
        acc += ((a0 + a1) + (a2 + a3)) + ((a4 + a5) + (a6 + a7));
    }
    for (; j < end; j += 4) {
        int r = s_adj[j];
        acc += xwsrc[r * 64 + lane] * s_dinv[r];
    }
    return acc;
}

// ---------------- gather1 fused with xw2 = h1 @ Wg2 ----------------
__global__ __launch_bounds__(256) void k_gather1(const int* __restrict__ adj,
                                                 const int* __restrict__ degI,
                                                 const float* __restrict__ xw1,
                                                 const float* __restrict__ Wg2,
                                                 const float* __restrict__ bg1,
                                                 float* __restrict__ xw2) {
    __shared__ float sW[4096];
    __shared__ float s_dinv[Nn];
    __shared__ int s_adj[CAP];
    __shared__ float red[4][64];
    int tid = threadIdx.x;
    int lane = tid & 63;
    int w = tid >> 6;
    int c = blockIdx.x;
    for (int i = tid; i < 1024; i += 256)
        ((float4*)sW)[i] = ((const float4*)Wg2)[i];
    {
        int4 d4 = ((const int4*)degI)[tid];
        s_dinv[4 * tid]     = rsqrtf((float)d4.x + 1.f);
        s_dinv[4 * tid + 1] = rsqrtf((float)d4.y + 1.f);
        s_dinv[4 * tid + 2] = rsqrtf((float)d4.z + 1.f);
        s_dinv[4 * tid + 3] = rsqrtf((float)d4.w + 1.f);
    }
    int n = __builtin_amdgcn_readfirstlane(degI[c]);
    if (n > CAP) n = CAP;
    if (tid < n) s_adj[tid] = adj[c * CAP + tid];
    __syncthreads();
    float acc = gather_quarter(s_adj, xw1, s_dinv, w, n, lane);
    red[w][lane] = acc;
    __syncthreads();
    if (w == 0) {
        float a = (red[0][lane] + red[1][lane]) + (red[2][lane] + red[3][lane]);
        float dc = s_dinv[c];
        float h1c = dc * a + dc * dc * xw1[c * 64 + lane] + bg1[lane];
        float t = 0.f;
        #pragma unroll 8
        for (int j = 0; j < 64; ++j) t = fmaf(__shfl(h1c, j), sW[j * 64 + lane], t);
        xw2[c * 64 + lane] = t;
    }
}

// ---------------- on-the-fly h2 row (one wave): h2[r] = dr*sum + dr^2*xw2[r] + bg2 ----------------
__device__ __forceinline__ float row_h2(const int* __restrict__ adj,
                                        const int* __restrict__ degI,
                                        const float* __restrict__ xw2,
                                        const float* s_dinv,
                                        const float* __restrict__ bg2,
                                        int r, int lane) {
    const int* al = adj + r * CAP;   // uniform address -> scalar loads
    int n = __builtin_amdgcn_readfirstlane(degI[r]);
    if (n > CAP) n = CAP;
    float acc = 0.f;
    int j = 0;
    for (; j + 7 < n; j += 8) {
        int r0 = al[j],     r1 = al[j + 1], r2 = al[j + 2], r3 = al[j + 3];
        int r4 = al[j + 4], r5 = al[j + 5], r6 = al[j + 6], r7 = al[j + 7];
        float a0 = xw2[r0 * 64 + lane] * s_dinv[r0];
        float a1 = xw2[r1 * 64 + lane] * s_dinv[r1];
        float a2 = xw2[r2 * 64 + lane] * s_dinv[r2];
        float a3 = xw2[r3 * 64 + lane] * s_dinv[r3];
        float a4 = xw2[r4 * 64 + lane] * s_dinv[r4];
        float a5 = xw2[r5 * 64 + lane] * s_dinv[r5];
        float a6 = xw2[r6 * 64 + lane] * s_dinv[r6];
        float a7 = xw2[r7 * 64 + lane] * s_dinv[r7];
        acc += ((a0 + a1) + (a2 + a3)) + ((a4 + a5) + (a6 + a7));
    }
    for (; j < n; ++j) {
        int rr = al[j];
        acc += xw2[rr * 64 + lane] * s_dinv[rr];
    }
    float dr = s_dinv[r];
    return dr * acc + dr * dr * xw2[r * 64 + lane] + bg2[lane];
}

// ---------------- fused: intersect + on-the-fly h2 + edge MLPs + final MLP ----------------
// 1 query/block, 512 threads = 8 waves. Waves 0/1 build h2[a],h2[b]; wave 2 builds hit list;
// all 8 waves round-robin hits (gather h2[k] + two MLP heads); LDS reduce; wave 0 final MLP.
__global__ __launch_bounds__(512) void k_posfinal2(
    const int* __restrict__ pos,
    const ull* __restrict__ Mbit, const ull* __restrict__ MTbit,
    const int* __restrict__ adj, const int* __restrict__ degI,
    const float* __restrict__ xw2, const float* __restrict__ bg2,
    const float* __restrict__ W1, const float* __restrict__ b1,
    const float* __restrict__ g1, const float* __restrict__ be1,
    const float* __restrict__ W2, const float* __restrict__ b2,
    const float* __restrict__ g2, const float* __restrict__ be2,
    const float* __restrict__ Wa, const float* __restrict__ ba,
    const float* __restrict__ Wb, const float* __restrict__ bb,
    float* __restrict__ out) {
    __shared__ float W1s[4096], W2s[4096];
    __shared__ float s_dinv[Nn];
    __shared__ float s_ha[64], s_hb[64];
    __shared__ float s_red[8][64];
    __shared__ int s_hits[64];
    __shared__ int s_nhit;
    int tid = threadIdx.x;
    int lane = tid & 63;
    int wv = tid >> 6;
    if (tid == 0) s_nhit = 0;
    for (int i = tid; i < 1024; i += 512) {
        ((float4*)W1s)[i] = ((const float4*)W1)[i];
        ((float4*)W2s)[i] = ((const float4*)W2)[i];
    }
    {
        int2 d2 = ((const int2*)degI)[tid];
        s_dinv[2 * tid]     = rsqrtf((float)d2.x + 1.f);
        s_dinv[2 * tid + 1] = rsqrtf((float)d2.y + 1.f);
    }
    int p = blockIdx.x;
    int a = __builtin_amdgcn_readfirstlane(pos[p]);
    int b = __builtin_amdgcn_readfirstlane(pos[Pq + p]);
    __syncthreads();

    if (wv == 0) {
        s_ha[lane] = row_h2(adj, degI, xw2, s_dinv, bg2, a, lane);
    } else if (wv == 1) {
        s_hb[lane] = row_h2(adj, degI, xw2, s_dinv, bg2, b, lane);
    } else if (wv == 2 && lane < 16) {
        ull bits = Mbit[a * 16 + lane] & MTbit[b * 16 + lane];
        while (bits) {
            int k = (lane << 6) + __ffsll(bits) - 1;
            bits &= bits - 1;
            int idx = atomicAdd(&s_nhit, 1);
            if (idx < 64) s_hits[idx] = k;
        }
    }
    __syncthreads();

    int nh = s_nhit;
    if (nh > 64) nh = 64;
    float ha = s_ha[lane], hb = s_hb[lane];
    float lb1 = b1[lane], lg1 = g1[lane], lbe1 = be1[lane];
    float lb2 = b2[lane], lg2 = g2[lane], lbe2 = be2[lane];
    float acc = 0.f;
    for (int i = wv; i < nh; i += 8) {
        int k = __builtin_amdgcn_readfirstlane(s_hits[i]);
        float hk = row_h2(adj, degI, xw2, s_dinv, bg2, k, lane);
        float xeA = ha * hk;  // edge (a,k) -> head2 (x2, left operand)
        float xeB = hk * hb;  // edge (k,b) -> head1 (x1, right operand)
        float a2 = lb2, a1 = lb1;
        #pragma unroll 8
        for (int j = 0; j < 64; ++j) {
            float vA = __shfl(xeA, j);
            float vB = __shfl(xeB, j);
            a2 = fmaf(vA, W2s[j * 64 + lane], a2);
            a1 = fmaf(vB, W1s[j * 64 + lane], a1);
        }
        float s2 = a2, q2 = a2 * a2, s1 = a1, q1 = a1 * a1;
        for (int off = 32; off; off >>= 1) {
            s2 += __shfl_xor(s2, off); q2 += __shfl_xor(q2, off);
            s1 += __shfl_xor(s1, off); q1 += __shfl_xor(q1, off);
        }
        float mu2 = s2 * (1.f / 64.f), mu1 = s1 * (1.f / 64.f);
        float v2 = q2 * (1.f / 64.f) - mu2 * mu2;
        float v1 = q1 * (1.f / 64.f) - mu1 * mu1;
        float r2v = rsqrtf(v2 + 1e-5f), r1v = rsqrtf(v1 + 1e-5f);
        float x2v = fmaxf(0.f, (a2 - mu2) * r2v * lg2 + lbe2);
        float x1v = fmaxf(0.f, (a1 - mu1) * r1v * lg1 + lbe1);
        acc += x2v * x1v;
    }
    s_red[wv][lane] = acc;
    __syncthreads();
    if (wv == 0) {
        float A = 0.f;
        #pragma unroll
        for (int w2i = 0; w2i < 8; ++w2i) A += s_red[w2i][lane];
        float xx = ha * hb;
        float t = ba[lane];
        #pragma unroll 8
        for (int j = 0; j < 64; ++j) {
            t = fmaf(__shfl(A, j), Wa[j * 64 + lane], t);
            t = fmaf(__shfl(xx, j), Wa[(64 + j) * 64 + lane], t);
        }
        t = fmaxf(t, 0.f);
        float v = t * Wb[lane];
        for (int off = 32; off; off >>= 1) v += __shfl_xor(v, off);
        if (lane == 0) out[p] = v + bb[0];
    }
}

extern "C" void kernel_launch(void* const* d_in, const int* in_sizes, int n_in,
                              void* d_out, int out_size, void* d_ws, size_t ws_size,
                              hipStream_t stream) {
    const float* x    = (const float*)d_in[0];
    const int*   ei   = (const int*)d_in[1];
    const int*   pos  = (const int*)d_in[2];
    const float* Wg1  = (const float*)d_in[3];
    const float* bg1  = (const float*)d_in[4];
    const float* Wg2  = (const float*)d_in[5];
    const float* bg2  = (const float*)d_in[6];
    const float* Wm1  = (const float*)d_in[7];
    const float* bm1  = (const float*)d_in[8];
    const float* gm1  = (const float*)d_in[9];
    const float* bem1 = (const float*)d_in[10];
    const float* Wm2  = (const float*)d_in[11];
    const float* bm2  = (const float*)d_in[12];
    const float* gm2  = (const float*)d_in[13];
    const float* bem2 = (const float*)d_in[14];
    const float* Wa   = (const float*)d_in[15];
    const float* ba   = (const float*)d_in[16];
    const float* Wb   = (const float*)d_in[17];
    const float* bb   = (const float*)d_in[18];
    float* out = (float*)d_out;

    char* w = (char*)d_ws;
    // --- zero-init region (266240 B) ---
    char* zbase = w;
    int* degI = (int*)w;  w += 1024 * 4;
    ull* Mbit = (ull*)w;  w += 1024 * 16 * 8;
    ull* MTbit = (ull*)w; w += 1024 * 16 * 8;
    // --- no-init ---
    int*   adj = (int*)w;   w += (size_t)Nn * CAP * 4;
    float* xw1 = (float*)w; w += 65536 * 4;
    float* xw2 = (float*)w; w += 65536 * 4;

    k_zero<<<65, 256, 0, stream>>>((uint4*)zbase);
    k_front<<<512, 256, 0, stream>>>(x, Wg1, xw1, ei, degI, adj, Mbit, MTbit);
    k_gather1<<<Nn, 256, 0, stream>>>(adj, degI, xw1, Wg2, bg1, xw2);
    k_posfinal2<<<Pq, 512, 0, stream>>>(pos, Mbit, MTbit, adj, degI, xw2, bg2,
                                        Wm1, bm1, gm1, bem1,
                                        Wm2, bm2, gm2, bem2,
                                        Wa, ba, Wb, bb, out);
}

// Round 15
// 63.720 us; speedup vs baseline: 1.0378x; 1.0378x over previous
//
#include <hip/hip_runtime.h>

#define Nn 1024
#define Ee 65536
#define Pq 1024
#define CAP 160

typedef unsigned long long ull;

// ---------------- zero-init ----------------
__global__ __launch_bounds__(256) void k_zero(uint4* __restrict__ z) {
    z[blockIdx.x * 256 + threadIdx.x] = make_uint4(0, 0, 0, 0);
}

// ---------------- fused front, role-split 512 blocks ----------------
// Blocks 0-255: xw1 = x @ Wg1. Blocks 256-511: edge pass (deg, padded adj, bitmaps).
__global__ __launch_bounds__(256) void k_front(const float* __restrict__ x,
                                               const float* __restrict__ Wg1,
                                               float* __restrict__ xw1,
                                               const int* __restrict__ ei,
                                               int* __restrict__ degI,
                                               int* __restrict__ adj,
                                               ull* __restrict__ Mbit,
                                               ull* __restrict__ MTbit) {
    __shared__ float sW[8192];
    int tid = threadIdx.x;
    int B = blockIdx.x;
    if (B < 256) {
        int gid = B * 256 + tid;
        for (int i = tid; i < 2048; i += 256)
            ((float4*)sW)[i] = ((const float4*)Wg1)[i];
        __syncthreads();
        int lane = gid & 63;
        int r = __builtin_amdgcn_readfirstlane(gid >> 6);
        const float* xr = x + r * 128;
        float acc = 0.f;
        #pragma unroll 8
        for (int j = 0; j < 128; ++j) acc = fmaf(xr[j], sW[j * 64 + lane], acc);
        xw1[gid] = acc;
    } else {
        int e = (B - 256) * 256 + tid;
        int r = ei[e], c = ei[Ee + e];
        int slot = atomicAdd(&degI[c], 1);
        if (slot < CAP) adj[c * CAP + slot] = r;
        atomicOr(&Mbit[r * 16 + (c >> 6)], 1ull << (c & 63));
        atomicOr(&MTbit[c * 16 + (r >> 6)], 1ull << (r & 63));
    }
}

// ---------------- gather core: LDS-resident adjacency, 4 waves split, 8-deep ILP ----------------
__device__ __forceinline__ float gather_quarter(const int* __restrict__ s_adj,
                                                const float* __restrict__ xwsrc,
                                                const float* s_dinv, int w,
                                                int n, int lane) {
    float acc = 0.f;
    int j = w, end = n;
    for (; j + 28 < end; j += 32) {
        int r0 = s_adj[j],      r1 = s_adj[j + 4],  r2 = s_adj[j + 8],  r3 = s_adj[j + 12];
        int r4 = s_adj[j + 16], r5 = s_adj[j + 20], r6 = s_adj[j + 24], r7 = s_adj[j + 28];
        float a0 = xwsrc[r0 * 64 + lane] * s_dinv[r0];
        float a1 = xwsrc[r1 * 64 + lane] * s_dinv[r1];
        float a2 = xwsrc[r2 * 64 + lane] * s_dinv[r2];
        float a3 = xwsrc[r3 * 64 + lane] * s_dinv[r3];
        float a4 = xwsrc[r4 * 64 + lane] * s_dinv[r4];
        float a5 = xwsrc[r5 * 64 + lane] * s_dinv[r5];
        float a6 = xwsrc[r6 * 64 + lane] * s_dinv[r6];
        float a7 = xwsrc[r7 * 64 + lane] * s_dinv[r7];
        acc += ((a0 + a1) + (a2 + a3)) + ((a4 + a5) + (a6 + a7));
    }
    for (; j < end; j += 4) {
        int r = s_adj[j];
        acc += xwsrc[r * 64 + lane] * s_dinv[r];
    }
    return acc;
}

// ---------------- gather1 fused with xw2 = h1 @ Wg2 ----------------
__global__ __launch_bounds__(256) void k_gather1(const int* __restrict__ adj,
                                                 const int* __restrict__ degI,
                                                 const float* __restrict__ xw1,
                                                 const float* __restrict__ Wg2,
                                                 const float* __restrict__ bg1,
                                                 float* __restrict__ xw2) {
    __shared__ float sW[4096];
    __shared__ float s_dinv[Nn];
    __shared__ int s_adj[CAP];
    __shared__ float red[4][64];
    int tid = threadIdx.x;
    int lane = tid & 63;
    int w = tid >> 6;
    int c = blockIdx.x;
    for (int i = tid; i < 1024; i += 256)
        ((float4*)sW)[i] = ((const float4*)Wg2)[i];
    {
        int4 d4 = ((const int4*)degI)[tid];
        s_dinv[4 * tid]     = rsqrtf((float)d4.x + 1.f);
        s_dinv[4 * tid + 1] = rsqrtf((float)d4.y + 1.f);
        s_dinv[4 * tid + 2] = rsqrtf((float)d4.z + 1.f);
        s_dinv[4 * tid + 3] = rsqrtf((float)d4.w + 1.f);
    }
    int n = __builtin_amdgcn_readfirstlane(degI[c]);
    if (n > CAP) n = CAP;
    if (tid < n) s_adj[tid] = adj[c * CAP + tid];
    __syncthreads();
    float acc = gather_quarter(s_adj, xw1, s_dinv, w, n, lane);
    red[w][lane] = acc;
    __syncthreads();
    if (w == 0) {
        float a = (red[0][lane] + red[1][lane]) + (red[2][lane] + red[3][lane]);
        float dc = s_dinv[c];
        float h1c = dc * a + dc * dc * xw1[c * 64 + lane] + bg1[lane];
        float t = 0.f;
        #pragma unroll 8
        for (int j = 0; j < 64; ++j) t = fmaf(__shfl(h1c, j), sW[j * 64 + lane], t);
        xw2[c * 64 + lane] = t;
    }
}

// ---------------- gather2 -> h2 ----------------
__global__ __launch_bounds__(256) void k_gather2(const int* __restrict__ adj,
                                                 const int* __restrict__ degI,
                                                 const float* __restrict__ xw2,
                                                 const float* __restrict__ bg2,
                                                 float* __restrict__ h2) {
    __shared__ float s_dinv[Nn];
    __shared__ int s_adj[CAP];
    __shared__ float red[4][64];
    int tid = threadIdx.x;
    int lane = tid & 63;
    int w = tid >> 6;
    int c = blockIdx.x;
    {
        int4 d4 = ((const int4*)degI)[tid];
        s_dinv[4 * tid]     = rsqrtf((float)d4.x + 1.f);
        s_dinv[4 * tid + 1] = rsqrtf((float)d4.y + 1.f);
        s_dinv[4 * tid + 2] = rsqrtf((float)d4.z + 1.f);
        s_dinv[4 * tid + 3] = rsqrtf((float)d4.w + 1.f);
    }
    int n = __builtin_amdgcn_readfirstlane(degI[c]);
    if (n > CAP) n = CAP;
    if (tid < n) s_adj[tid] = adj[c * CAP + tid];
    __syncthreads();
    float acc = gather_quarter(s_adj, xw2, s_dinv, w, n, lane);
    red[w][lane] = acc;
    __syncthreads();
    if (w == 0) {
        float a = (red[0][lane] + red[1][lane]) + (red[2][lane] + red[3][lane]);
        float dc = s_dinv[c];
        h2[c * 64 + lane] = dc * a + dc * dc * xw2[c * 64 + lane] + bg2[lane];
    }
}

// ---------------- fused: bitmap intersect -> on-the-fly edge MLPs -> final MLP ----------------
// 1 query per block; 4 waves split bitmap words wd === wv (mod 4); LDS combine.
__global__ __launch_bounds__(256) void k_posfinal(
    const int* __restrict__ pos,
    const ull* __restrict__ Mbit, const ull* __restrict__ MTbit,
    const float* __restrict__ h2,
    const float* __restrict__ W1, const float* __restrict__ b1,
    const float* __restrict__ g1, const float* __restrict__ be1,
    const float* __restrict__ W2, const float* __restrict__ b2,
    const float* __restrict__ g2, const float* __restrict__ be2,
    const float* __restrict__ Wa, const float* __restrict__ ba,
    const float* __restrict__ Wb, const float* __restrict__ bb,
    float* __restrict__ out) {
    __shared__ float W1s[4096], W2s[4096];
    __shared__ float s_red[3][64];
    int tid = threadIdx.x;
    for (int i = tid; i < 1024; i += 256) {
        ((float4*)W1s)[i] = ((const float4*)W1)[i];
        ((float4*)W2s)[i] = ((const float4*)W2)[i];
    }
    __syncthreads();
    int lane = tid & 63;
    int wv = tid >> 6;
    int p = blockIdx.x;
    int a = __builtin_amdgcn_readfirstlane(pos[p]);
    int b = __builtin_amdgcn_readfirstlane(pos[Pq + p]);
    float ha = h2[a * 64 + lane], hb = h2[b * 64 + lane];
    float lb1 = b1[lane], lg1 = g1[lane], lbe1 = be1[lane];
    float lb2 = b2[lane], lg2 = g2[lane], lbe2 = be2[lane];
    float acc = 0.f;
    for (int wd = wv; wd < 16; wd += 4) {
        ull bits = Mbit[a * 16 + wd] & MTbit[b * 16 + wd];
        while (bits) {
            int k = (wd << 6) + __ffsll(bits) - 1;
            bits &= bits - 1;
            float hk = h2[k * 64 + lane];
            float xeA = ha * hk;  // edge (a,k) -> head2 (x2, left operand)
            float xeB = hk * hb;  // edge (k,b) -> head1 (x1, right operand)
            float a2 = lb2, a1 = lb1;
            #pragma unroll 8
            for (int j = 0; j < 64; ++j) {
                float vA = __shfl(xeA, j);
                float vB = __shfl(xeB, j);
                a2 = fmaf(vA, W2s[j * 64 + lane], a2);
                a1 = fmaf(vB, W1s[j * 64 + lane], a1);
            }
            float s2 = a2, q2 = a2 * a2, s1 = a1, q1 = a1 * a1;
            for (int off = 32; off; off >>= 1) {
                s2 += __shfl_xor(s2, off); q2 += __shfl_xor(q2, off);
                s1 += __shfl_xor(s1, off); q1 += __shfl_xor(q1, off);
            }
            float mu2 = s2 * (1.f / 64.f), mu1 = s1 * (1.f / 64.f);
            float v2 = q2 * (1.f / 64.f) - mu2 * mu2;
            float v1 = q1 * (1.f / 64.f) - mu1 * mu1;
            float r2v = rsqrtf(v2 + 1e-5f), r1v = rsqrtf(v1 + 1e-5f);
            float x2v = fmaxf(0.f, (a2 - mu2) * r2v * lg2 + lbe2);
            float x1v = fmaxf(0.f, (a1 - mu1) * r1v * lg1 + lbe1);
            acc += x2v * x1v;
        }
    }
    if (wv) s_red[wv - 1][lane] = acc;
    __syncthreads();
    if (wv == 0) {
        acc += (s_red[0][lane] + s_red[1][lane]) + s_red[2][lane];
        float xx = ha * hb;
        float t = ba[lane];
        #pragma unroll 8
        for (int j = 0; j < 64; ++j) {
            t = fmaf(__shfl(acc, j), Wa[j * 64 + lane], t);
            t = fmaf(__shfl(xx, j), Wa[(64 + j) * 64 + lane], t);
        }
        t = fmaxf(t, 0.f);
        float v = t * Wb[lane];
        for (int off = 32; off; off >>= 1) v += __shfl_xor(v, off);
        if (lane == 0) out[p] = v + bb[0];
    }
}

extern "C" void kernel_launch(void* const* d_in, const int* in_sizes, int n_in,
                              void* d_out, int out_size, void* d_ws, size_t ws_size,
                              hipStream_t stream) {
    const float* x    = (const float*)d_in[0];
    const int*   ei   = (const int*)d_in[1];
    const int*   pos  = (const int*)d_in[2];
    const float* Wg1  = (const float*)d_in[3];
    const float* bg1  = (const float*)d_in[4];
    const float* Wg2  = (const float*)d_in[5];
    const float* bg2  = (const float*)d_in[6];
    const float* Wm1  = (const float*)d_in[7];
    const float* bm1  = (const float*)d_in[8];
    const float* gm1  = (const float*)d_in[9];
    const float* bem1 = (const float*)d_in[10];
    const float* Wm2  = (const float*)d_in[11];
    const float* bm2  = (const float*)d_in[12];
    const float* gm2  = (const float*)d_in[13];
    const float* bem2 = (const float*)d_in[14];
    const float* Wa   = (const float*)d_in[15];
    const float* ba   = (const float*)d_in[16];
    const float* Wb   = (const float*)d_in[17];
    const float* bb   = (const float*)d_in[18];
    float* out = (float*)d_out;

    char* w = (char*)d_ws;
    // --- zero-init region (266240 B = 16640 uint4 = 65 blocks x 256) ---
    char* zbase = w;
    int* degI = (int*)w;  w += 1024 * 4;
    ull* Mbit = (ull*)w;  w += 1024 * 16 * 8;
    ull* MTbit = (ull*)w; w += 1024 * 16 * 8;
    // --- no-init ---
    int*   adj = (int*)w;   w += (size_t)Nn * CAP * 4;
    float* xw1 = (float*)w; w += 65536 * 4;
    float* xw2 = (float*)w; w += 65536 * 4;
    float* h2  = (float*)w; w += 65536 * 4;

    k_zero<<<65, 256, 0, stream>>>((uint4*)zbase);
    k_front<<<512, 256, 0, stream>>>(x, Wg1, xw1, ei, degI, adj, Mbit, MTbit);
    k_gather1<<<Nn, 256, 0, stream>>>(adj, degI, xw1, Wg2, bg1, xw2);
    k_gather2<<<Nn, 256, 0, stream>>>(adj, degI, xw2, bg2, h2);
    k_posfinal<<<Pq, 256, 0, stream>>>(pos, Mbit, MTbit, h2,
                                       Wm1, bm1, gm1, bem1,
                                       Wm2, bm2, gm2, bem2,
                                       Wa, ba, Wb, bb, out);
}